// Round 14
// baseline (953.679 us; speedup 1.0000x reference)
//
#include <hip/hip_runtime.h>
#include <stdint.h>

#define DB   8
#define DC   64
#define DLX  256
#define DLY  256
#define DD   768
#define DH0  1536
#define DH1  768
#define NBC  (DB*DC)        // 512
#define NTOK (NBC*DLX)      // 131072
#define TAU  0.25f

typedef float f32x4 __attribute__((ext_vector_type(4)));
typedef _Float16 f16x8 __attribute__((ext_vector_type(8)));
typedef _Float16 f16x4 __attribute__((ext_vector_type(4)));

// fast softplus via hw exp2/log2
__device__ __forceinline__ float softplusf(float x){
  float t = __builtin_amdgcn_exp2f(-fabsf(x) * 1.44269504f);
  return fmaxf(x, 0.0f) + 0.69314718f * __builtin_amdgcn_logf(1.0f + t);
}

// async global->LDS, 16B per lane; lds base wave-uniform (linear dest)
__device__ __forceinline__ void gload_lds16(const void* g, void* l){
  __builtin_amdgcn_global_load_lds((const __attribute__((address_space(1))) void*)g,
                                   (__attribute__((address_space(3))) void*)l,
                                   16, 0, 0);
}

// ---------------- fp32 -> f16 conversion (strided submatrix; weights + xs only) ----------------
__global__ __launch_bounds__(256) void k_cvt16(const float* __restrict__ src, int ld, int off,
                                               int rows, int cols, _Float16* __restrict__ dst){
  int total = rows * (cols >> 3);
  for (int idx = blockIdx.x * 256 + threadIdx.x; idx < total; idx += gridDim.x * 256){
    int r = idx / (cols >> 3), c8 = (idx % (cols >> 3)) * 8;
    const float* s = src + (size_t)r * ld + off + c8;
    float4 f0 = *(const float4*)s, f1 = *(const float4*)(s + 4);
    f16x8 v;
    v[0]=(_Float16)f0.x; v[1]=(_Float16)f0.y; v[2]=(_Float16)f0.z; v[3]=(_Float16)f0.w;
    v[4]=(_Float16)f1.x; v[5]=(_Float16)f1.y; v[6]=(_Float16)f1.z; v[7]=(_Float16)f1.w;
    *(f16x8*)(dst + (size_t)r * cols + c8) = v;
  }
}

// ---------------- scores + fused ys->f16 (R13, verified) ----------------
__global__ __launch_bounds__(1024, 2) void k_scores4(const _Float16* __restrict__ xs16,
                                                     const float* __restrict__ ys,
                                                     const float* __restrict__ xs,
                                                     _Float16* __restrict__ ys16,
                                                     int* __restrict__ widx){
  const int bc = blockIdx.x, b = bc >> 6;
  const float* Y = ys + (size_t)bc * DLY * DD;
  __shared__ __align__(16) _Float16 As[256 * 32];   // 16 KB
  __shared__ __align__(16) _Float16 Bs[256 * 32];   // 16 KB
  __shared__ float rmx[256][4];
  __shared__ float gm[256];
  __shared__ unsigned short cand[256][8];
  __shared__ int ccnt[256];
  const int tid = threadIdx.x;
  const int l = tid & 63, w = tid >> 6;     // 16 waves
  const int wr = w >> 2, wc = w & 3;        // wave tile 64m x 64n
  const int lrow = l & 15, lg = l >> 4;
  const int kq = (lg ^ (lrow & 3)) * 8;     // swizzled read col (halves)
  const int kg = (((l & 3) ^ ((l >> 2) & 3))) * 8;
  const _Float16* srcA = xs16 + ((size_t)b * DLX + w*16 + (l >> 2)) * DD + kg;
  const int r = tid >> 2, c8 = (tid & 3) * 8;
  const float* srcB = Y + (size_t)r * DD + c8;
  _Float16* ydst = ys16 + ((size_t)bc * DLY + r) * DD + c8;
  const int bslot = (((tid & 3) ^ (r & 3))) * 8;

  f32x4 acc[4][4];
  #pragma unroll
  for (int i = 0; i < 4; i++)
    #pragma unroll
    for (int j = 0; j < 4; j++) acc[i][j] = (f32x4){0.f,0.f,0.f,0.f};

  for (int k0 = 0; k0 < DD; k0 += 32){
    float4 f0 = *(const float4*)(srcB + k0);
    float4 f1 = *(const float4*)(srcB + k0 + 4);
    f16x8 hv;
    hv[0]=(_Float16)f0.x; hv[1]=(_Float16)f0.y; hv[2]=(_Float16)f0.z; hv[3]=(_Float16)f0.w;
    hv[4]=(_Float16)f1.x; hv[5]=(_Float16)f1.y; hv[6]=(_Float16)f1.z; hv[7]=(_Float16)f1.w;
    __syncthreads();
    gload_lds16(srcA + k0, As + w*512);
    *(f16x8*)&Bs[r*32 + bslot] = hv;
    *(f16x8*)(ydst + k0) = hv;
    __syncthreads();
    f16x8 af[4], bf[4];
    #pragma unroll
    for (int i = 0; i < 4; i++){
      af[i] = *(const f16x8*)&As[(wr*64 + i*16 + lrow)*32 + kq];
      bf[i] = *(const f16x8*)&Bs[(wc*64 + i*16 + lrow)*32 + kq];
    }
    #pragma unroll
    for (int i = 0; i < 4; i++)
      #pragma unroll
      for (int j = 0; j < 4; j++)
        acc[i][j] = __builtin_amdgcn_mfma_f32_16x16x32_f16(af[i], bf[j], acc[i][j], 0, 0, 0);
  }

  #pragma unroll
  for (int i = 0; i < 4; i++)
    #pragma unroll
    for (int r2 = 0; r2 < 4; r2++){
      float m = fmaxf(fmaxf(acc[i][0][r2], acc[i][1][r2]), fmaxf(acc[i][2][r2], acc[i][3][r2]));
      m = fmaxf(m, __shfl_xor(m, 1));
      m = fmaxf(m, __shfl_xor(m, 2));
      m = fmaxf(m, __shfl_xor(m, 4));
      m = fmaxf(m, __shfl_xor(m, 8));
      if (lrow == 0) rmx[wr*64 + i*16 + lg*4 + r2][wc] = m;
    }
  __syncthreads();
  if (tid < 256){
    gm[tid] = fmaxf(fmaxf(rmx[tid][0], rmx[tid][1]), fmaxf(rmx[tid][2], rmx[tid][3]));
    ccnt[tid] = 0;
  }
  __syncthreads();
  #pragma unroll
  for (int i = 0; i < 4; i++)
    #pragma unroll
    for (int r2 = 0; r2 < 4; r2++){
      int t = wr*64 + i*16 + lg*4 + r2;
      float thr = gm[t] - TAU;
      #pragma unroll
      for (int j = 0; j < 4; j++){
        float s = acc[i][j][r2];
        if (s >= thr){
          int p = atomicAdd(&ccnt[t], 1);
          if (p < 8) cand[t][p] = (unsigned short)(wc*64 + j*16 + lrow);
        }
      }
    }
  __syncthreads();
  for (int it = 0; it < 16; it++){
    int t = w * 16 + it;
    int cnt = ccnt[t];
    int by;
    if (cnt == 1){
      by = cand[t][0];
    } else {
      const float* xr = xs + ((size_t)b * DLX + t) * DD;
      float best = -1e30f; int besty = 0;
      int n = (cnt <= 8) ? cnt : 256;
      for (int p = 0; p < n; p++){
        int c = (cnt <= 8) ? (int)cand[t][p] : p;
        const float* yr = Y + (size_t)c * DD;
        float s = 0.f;
        #pragma unroll
        for (int q = 0; q < 3; q++){
          float4 xv = *(const float4*)(xr + l*12 + q*4);
          float4 yv = *(const float4*)(yr + l*12 + q*4);
          s += xv.x*yv.x + xv.y*yv.y + xv.z*yv.z + xv.w*yv.w;
        }
        s += __shfl_xor(s, 1);  s += __shfl_xor(s, 2);  s += __shfl_xor(s, 4);
        s += __shfl_xor(s, 8);  s += __shfl_xor(s, 16); s += __shfl_xor(s, 32);
        if (s > best || (s == best && c < besty)){ best = s; besty = c; }
      }
      by = besty;
    }
    if (l == 0) widx[(size_t)bc * DLX + t] = by;
  }
}

// ---------------- 128x256 f16 MFMA GEMM, 8 waves, BK=32, TRIPLE-buffer depth-2 ----------------
// Per step T: issue L(T+2) -> vmcnt(3) [waits L(T+1); L(T) already guaranteed] -> barrier
//             -> ds_read + 16 MFMA from buf[T%3] -> barrier.
// Buffer reuse distance 3; stores for T+2 issued after the barrier that freed that buffer.
// LDS 3 x 24KB = 72KB -> 2 blocks/CU preserved.
// MODE 0: X0h = f16(xs16 @ W0x^T + b0)               (grid 6 x 16)
// MODE 1: H0 = softplus(ys16[widx] @ W0y^T + X0h)    (grid 6 x 1024)
// MODE 2: spart = softplus(H0 @ W1^T + b1) . w2      (grid 3 x 1024)
template<int MODE>
__global__ __launch_bounds__(512) void k_gemm16(const _Float16* __restrict__ A,
        unsigned bdelta,                       // (B - A) in halves
        const int* __restrict__ widx,
        const _Float16* __restrict__ X0h,
        const float* __restrict__ bias,
        const float* __restrict__ w2,
        float* __restrict__ outF,
        _Float16* __restrict__ outH){
  constexpr int K = (MODE == 2) ? DH0 : DD;
  constexpr int NT = K / 32;                        // 24 or 48 steps
  constexpr unsigned BUFH = 12288;                  // halves per buffer (A 4096 + B 8192)
  __shared__ __align__(16) _Float16 S[3 * BUFH];    // 72 KB
  const int tid = threadIdx.x;
  const int gx = gridDim.x, nwg = gx * gridDim.y;
  int lin = blockIdx.x + gx * blockIdx.y;
  int swz = (lin & 7) * (nwg >> 3) + (lin >> 3);   // bijective (nwg % 8 == 0)
  const int n0  = (swz % gx) * 256;
  const int by  = swz / gx;
  const int rt0 = by * 128;
  const int l = tid & 63, w = tid >> 6;            // 8 waves
  const int wr = w >> 2, wc = w & 3;               // wave tile 64m x 64n
  const int lrow = l & 15, lg = l >> 4;
  const int kq = (lg ^ (lrow & 3)) * 8;            // swizzled read col (R8-verified)

  int bc = 0, xb = 0, b = 0;
  if constexpr (MODE == 1){ bc = by >> 1; xb = (by & 1) * 128; b = bc >> 6; }

  // staging: 24 1KB-units/step (0..7 = A 16-row groups, 8..23 = B), 3 per wave.
  // lane l -> in-unit row (l>>2), dest slot (l&3); source slot (l&3)^(row&3).
  const int urow = l >> 2;
  const int kg = (((l & 3) ^ (urow & 3))) * 8;     // pre-swizzled source col (halves)
  unsigned goff[3];                                // halves offset from A base (k0=0)
  unsigned ldoff[3];                               // halves offset within a buffer
  #pragma unroll
  for (int i = 0; i < 3; i++){
    int u = w*3 + i;
    if (u < 8){
      int row = u*16 + urow;
      unsigned aoff;
      if constexpr (MODE == 1){
        int yi = widx[bc * DLX + xb + row];
        aoff = (unsigned)((bc * DLY + yi) * DD);
      } else {
        aoff = (unsigned)((rt0 + row) * K);
      }
      goff[i] = aoff + kg;
      ldoff[i] = u * 512;
    } else {
      int row = (u - 8)*16 + urow;
      goff[i] = bdelta + (unsigned)((n0 + row) * K) + kg;
      ldoff[i] = 4096 + (u - 8) * 512;
    }
  }

  f32x4 acc[4][4];
  #pragma unroll
  for (int i = 0; i < 4; i++)
    #pragma unroll
    for (int j = 0; j < 4; j++) acc[i][j] = (f32x4){0.f,0.f,0.f,0.f};

  // prologue: stage steps 0 and 1
  #pragma unroll
  for (int i = 0; i < 3; i++) gload_lds16(A + (size_t)goff[i], &S[ldoff[i]]);
  #pragma unroll
  for (int i = 0; i < 3; i++) gload_lds16(A + (size_t)(goff[i] + 32u), &S[BUFH + ldoff[i]]);

  unsigned oc = 0, on = BUFH, os = 2*BUFH;         // compute / next / stage-target
  for (int T = 0; T < NT; T++){
    if (T + 2 < NT){
      #pragma unroll
      for (int i = 0; i < 3; i++)
        gload_lds16(A + (size_t)(goff[i] + (unsigned)((T+2)*32)), &S[os + ldoff[i]]);
      asm volatile("s_waitcnt vmcnt(3)" ::: "memory");
    } else {
      asm volatile("s_waitcnt vmcnt(0)" ::: "memory");
    }
    __builtin_amdgcn_s_barrier();
    const _Float16* Sb = &S[oc];
    f16x8 af[4], bf[4];
    #pragma unroll
    for (int i = 0; i < 4; i++){
      af[i] = *(const f16x8*)&Sb[(wr*64 + i*16 + lrow)*32 + kq];
      bf[i] = *(const f16x8*)&Sb[4096 + (wc*64 + i*16 + lrow)*32 + kq];
    }
    #pragma unroll
    for (int i = 0; i < 4; i++)
      #pragma unroll
      for (int j = 0; j < 4; j++)
        acc[i][j] = __builtin_amdgcn_mfma_f32_16x16x32_f16(af[i], bf[j], acc[i][j], 0, 0, 0);
    __builtin_amdgcn_s_barrier();
    unsigned t = oc; oc = on; on = os; os = t;
  }

  if constexpr (MODE == 0){
    #pragma unroll
    for (int mi = 0; mi < 4; mi++)
      #pragma unroll
      for (int ni = 0; ni < 4; ni++){
        int n = n0 + wc*64 + ni*16 + lrow;
        float bv = bias[n];
        #pragma unroll
        for (int r = 0; r < 4; r++){
          int m = wr*64 + mi*16 + lg*4 + r;
          outH[(size_t)(rt0 + m) * DH0 + n] = (_Float16)(acc[mi][ni][r] + bv);
        }
      }
  } else if constexpr (MODE == 1){
    #pragma unroll
    for (int mi = 0; mi < 4; mi++)
      #pragma unroll
      for (int ni = 0; ni < 4; ni++){
        int n = n0 + wc*64 + ni*16 + lrow;
        #pragma unroll
        for (int r = 0; r < 4; r++){
          int m = wr*64 + mi*16 + lg*4 + r;
          float x0v = (float)X0h[((size_t)b * DLX + xb + m) * DH0 + n];
          float v = softplusf(acc[mi][ni][r] + x0v);
          outH[(size_t)(rt0 + m) * DH0 + n] = (_Float16)v;
        }
      }
  } else {
    float p[4][4];
    #pragma unroll
    for (int mi = 0; mi < 4; mi++)
      #pragma unroll
      for (int r = 0; r < 4; r++) p[mi][r] = 0.f;
    #pragma unroll
    for (int ni = 0; ni < 4; ni++){
      int n = n0 + wc*64 + ni*16 + lrow;
      float b1v = bias[n], w2v = w2[n];
      #pragma unroll
      for (int mi = 0; mi < 4; mi++)
        #pragma unroll
        for (int r = 0; r < 4; r++)
          p[mi][r] += softplusf(acc[mi][ni][r] + b1v) * w2v;
    }
    const int nb = (int)(swz % gx);
    #pragma unroll
    for (int mi = 0; mi < 4; mi++)
      #pragma unroll
      for (int r = 0; r < 4; r++){
        float s = p[mi][r];
        s += __shfl_xor(s, 1);
        s += __shfl_xor(s, 2);
        s += __shfl_xor(s, 4);
        s += __shfl_xor(s, 8);
        if (lrow == 0){
          size_t t = (size_t)rt0 + wr*64 + mi*16 + lg*4 + r;
          outF[t * 12 + nb*4 + wc] = s;
        }
      }
  }
}

// ---------------- final reduce ----------------
__global__ __launch_bounds__(256) void k_reduce(const float* __restrict__ spart,
                                                const float* __restrict__ b2,
                                                float* __restrict__ out){
  int bc = blockIdx.x, tid = threadIdx.x;
  const float* p = spart + ((size_t)bc * DLX + tid) * 12;
  float s = 0.0f;
  #pragma unroll
  for (int j = 0; j < 12; j++) s += p[j];
  __shared__ float red[256];
  red[tid] = s;
  __syncthreads();
  for (int off = 128; off > 0; off >>= 1){
    if (tid < off) red[tid] += red[tid + off];
    __syncthreads();
  }
  if (tid == 0) out[bc] = red[0] + 256.0f * b2[0];
}

extern "C" void kernel_launch(void* const* d_in, const int* in_sizes, int n_in,
                              void* d_out, int out_size, void* d_ws, size_t ws_size,
                              hipStream_t stream){
  const float* xs = (const float*)d_in[0];
  const float* ys = (const float*)d_in[1];
  const float* W0 = (const float*)d_in[2];
  const float* b0 = (const float*)d_in[3];
  const float* W1 = (const float*)d_in[4];
  const float* b1 = (const float*)d_in[5];
  const float* W2 = (const float*)d_in[6];
  const float* b2 = (const float*)d_in[7];
  float* out = (float*)d_out;

  char* wsp = (char*)d_ws;
  size_t off = 0;
  auto alloc = [&](size_t bytes)->void*{
    void* p = wsp + off;
    off += (bytes + 255) & ~(size_t)255;
    return p;
  };
  // adjacency groups for 32-bit B-deltas: (ys16, W0yf), (xs16, W0xf), (H0, W1f)
  int* widx        = (int*)alloc((size_t)NTOK * 4);
  _Float16* ys16   = (_Float16*)alloc((size_t)NBC * DLY * DD * 2);   // 201 MB
  _Float16* W0yf   = (_Float16*)alloc((size_t)DH0 * DD * 2);
  _Float16* xs16   = (_Float16*)alloc((size_t)DB * DLX * DD * 2);
  _Float16* W0xf   = (_Float16*)alloc((size_t)DH0 * DD * 2);
  _Float16* X0h    = (_Float16*)alloc((size_t)DB * DLX * DH0 * 2);   // 6.3 MB
  float* spart     = (float*)alloc((size_t)NTOK * 12 * 4);           // 6.3 MB
  _Float16* H0     = (_Float16*)alloc((size_t)NTOK * DH0 * 2);       // 402 MB
  _Float16* W1f    = (_Float16*)alloc((size_t)DH1 * DH0 * 2);

  unsigned d0 = (unsigned)(W0xf - xs16);
  unsigned d1 = (unsigned)(W0yf - ys16);
  unsigned d2 = (unsigned)(W1f - H0);

  k_cvt16<<<dim3(576),  256, 0, stream>>>(W0, DH0, 0,  DH0, DD, W0xf);
  k_cvt16<<<dim3(576),  256, 0, stream>>>(W0, DH0, DD, DH0, DD, W0yf);
  k_cvt16<<<dim3(576),  256, 0, stream>>>(W1, DH0, 0,  DH1, DH0, W1f);
  k_cvt16<<<dim3(768),  256, 0, stream>>>(xs, DD, 0, DB*DLX, DD, xs16);
  k_scores4<<<dim3(NBC), 1024, 0, stream>>>(xs16, ys, xs, ys16, widx);
  k_gemm16<0><<<dim3(6, 16),   512, 0, stream>>>(xs16, d0, nullptr, nullptr, b0, nullptr, nullptr, X0h);
  k_gemm16<1><<<dim3(6, 1024), 512, 0, stream>>>(ys16, d1, widx, X0h, nullptr, nullptr, nullptr, H0);
  k_gemm16<2><<<dim3(3, 1024), 512, 0, stream>>>(H0, d2, nullptr, nullptr, b1, W2, spart, nullptr);
  k_reduce<<<NBC, 256, 0, stream>>>(spart, b2, out);
}

// Round 15
// 919.901 us; speedup vs baseline: 1.0367x; 1.0367x over previous
//
#include <hip/hip_runtime.h>
#include <stdint.h>

#define DB   8
#define DC   64
#define DLX  256
#define DLY  256
#define DD   768
#define DH0  1536
#define DH1  768
#define NBC  (DB*DC)        // 512
#define NTOK (NBC*DLX)      // 131072
#define TAU  0.25f

typedef float f32x4 __attribute__((ext_vector_type(4)));
typedef _Float16 f16x8 __attribute__((ext_vector_type(8)));
typedef _Float16 f16x4 __attribute__((ext_vector_type(4)));

// fast softplus via hw exp2/log2
__device__ __forceinline__ float softplusf(float x){
  float t = __builtin_amdgcn_exp2f(-fabsf(x) * 1.44269504f);
  return fmaxf(x, 0.0f) + 0.69314718f * __builtin_amdgcn_logf(1.0f + t);
}

// async global->LDS, 16B per lane; lds base wave-uniform (linear dest)
__device__ __forceinline__ void gload_lds16(const void* g, void* l){
  __builtin_amdgcn_global_load_lds((const __attribute__((address_space(1))) void*)g,
                                   (__attribute__((address_space(3))) void*)l,
                                   16, 0, 0);
}

// ---------------- merged fp32 -> f16 conversion: W0x | W0y | W1 | xs in one launch ----------------
// block ranges: [0,576) W0x, [576,1152) W0y, [1152,1728) W1, [1728,2496) xs (exact sizes)
__global__ __launch_bounds__(256) void k_cvtall(const float* __restrict__ W0,
                                                const float* __restrict__ W1,
                                                const float* __restrict__ xs,
                                                _Float16* __restrict__ W0xf,
                                                _Float16* __restrict__ W0yf,
                                                _Float16* __restrict__ W1f,
                                                _Float16* __restrict__ xs16){
  const float* src; _Float16* dst; int ld, off, cols, idx;
  int bb = blockIdx.x;
  if (bb < 576){        src = W0; dst = W0xf; ld = DH0; off = 0;  cols = DD;  idx = bb*256 + threadIdx.x; }
  else if (bb < 1152){  src = W0; dst = W0yf; ld = DH0; off = DD; cols = DD;  idx = (bb-576)*256 + threadIdx.x; }
  else if (bb < 1728){  src = W1; dst = W1f;  ld = DH0; off = 0;  cols = DH0; idx = (bb-1152)*256 + threadIdx.x; }
  else {                src = xs; dst = xs16; ld = DD;  off = 0;  cols = DD;  idx = (bb-1728)*256 + threadIdx.x; }
  int r = idx / (cols >> 3), c8 = (idx % (cols >> 3)) * 8;
  const float* s = src + (size_t)r * ld + off + c8;
  float4 f0 = *(const float4*)s, f1 = *(const float4*)(s + 4);
  f16x8 v;
  v[0]=(_Float16)f0.x; v[1]=(_Float16)f0.y; v[2]=(_Float16)f0.z; v[3]=(_Float16)f0.w;
  v[4]=(_Float16)f1.x; v[5]=(_Float16)f1.y; v[6]=(_Float16)f1.z; v[7]=(_Float16)f1.w;
  *(f16x8*)(dst + (size_t)r * cols + c8) = v;
}

// ---------------- scores + fused ys->f16 (R13, verified) ----------------
__global__ __launch_bounds__(1024, 2) void k_scores4(const _Float16* __restrict__ xs16,
                                                     const float* __restrict__ ys,
                                                     const float* __restrict__ xs,
                                                     _Float16* __restrict__ ys16,
                                                     int* __restrict__ widx){
  const int bc = blockIdx.x, b = bc >> 6;
  const float* Y = ys + (size_t)bc * DLY * DD;
  __shared__ __align__(16) _Float16 As[256 * 32];   // 16 KB
  __shared__ __align__(16) _Float16 Bs[256 * 32];   // 16 KB
  __shared__ float rmx[256][4];
  __shared__ float gm[256];
  __shared__ unsigned short cand[256][8];
  __shared__ int ccnt[256];
  const int tid = threadIdx.x;
  const int l = tid & 63, w = tid >> 6;     // 16 waves
  const int wr = w >> 2, wc = w & 3;        // wave tile 64m x 64n
  const int lrow = l & 15, lg = l >> 4;
  const int kq = (lg ^ (lrow & 3)) * 8;     // swizzled read col (halves)
  const int kg = (((l & 3) ^ ((l >> 2) & 3))) * 8;
  const _Float16* srcA = xs16 + ((size_t)b * DLX + w*16 + (l >> 2)) * DD + kg;
  const int r = tid >> 2, c8 = (tid & 3) * 8;
  const float* srcB = Y + (size_t)r * DD + c8;
  _Float16* ydst = ys16 + ((size_t)bc * DLY + r) * DD + c8;
  const int bslot = (((tid & 3) ^ (r & 3))) * 8;

  f32x4 acc[4][4];
  #pragma unroll
  for (int i = 0; i < 4; i++)
    #pragma unroll
    for (int j = 0; j < 4; j++) acc[i][j] = (f32x4){0.f,0.f,0.f,0.f};

  for (int k0 = 0; k0 < DD; k0 += 32){
    float4 f0 = *(const float4*)(srcB + k0);
    float4 f1 = *(const float4*)(srcB + k0 + 4);
    f16x8 hv;
    hv[0]=(_Float16)f0.x; hv[1]=(_Float16)f0.y; hv[2]=(_Float16)f0.z; hv[3]=(_Float16)f0.w;
    hv[4]=(_Float16)f1.x; hv[5]=(_Float16)f1.y; hv[6]=(_Float16)f1.z; hv[7]=(_Float16)f1.w;
    __syncthreads();
    gload_lds16(srcA + k0, As + w*512);
    *(f16x8*)&Bs[r*32 + bslot] = hv;
    *(f16x8*)(ydst + k0) = hv;
    __syncthreads();
    f16x8 af[4], bf[4];
    #pragma unroll
    for (int i = 0; i < 4; i++){
      af[i] = *(const f16x8*)&As[(wr*64 + i*16 + lrow)*32 + kq];
      bf[i] = *(const f16x8*)&Bs[(wc*64 + i*16 + lrow)*32 + kq];
    }
    #pragma unroll
    for (int i = 0; i < 4; i++)
      #pragma unroll
      for (int j = 0; j < 4; j++)
        acc[i][j] = __builtin_amdgcn_mfma_f32_16x16x32_f16(af[i], bf[j], acc[i][j], 0, 0, 0);
  }

  #pragma unroll
  for (int i = 0; i < 4; i++)
    #pragma unroll
    for (int r2 = 0; r2 < 4; r2++){
      float m = fmaxf(fmaxf(acc[i][0][r2], acc[i][1][r2]), fmaxf(acc[i][2][r2], acc[i][3][r2]));
      m = fmaxf(m, __shfl_xor(m, 1));
      m = fmaxf(m, __shfl_xor(m, 2));
      m = fmaxf(m, __shfl_xor(m, 4));
      m = fmaxf(m, __shfl_xor(m, 8));
      if (lrow == 0) rmx[wr*64 + i*16 + lg*4 + r2][wc] = m;
    }
  __syncthreads();
  if (tid < 256){
    gm[tid] = fmaxf(fmaxf(rmx[tid][0], rmx[tid][1]), fmaxf(rmx[tid][2], rmx[tid][3]));
    ccnt[tid] = 0;
  }
  __syncthreads();
  #pragma unroll
  for (int i = 0; i < 4; i++)
    #pragma unroll
    for (int r2 = 0; r2 < 4; r2++){
      int t = wr*64 + i*16 + lg*4 + r2;
      float thr = gm[t] - TAU;
      #pragma unroll
      for (int j = 0; j < 4; j++){
        float s = acc[i][j][r2];
        if (s >= thr){
          int p = atomicAdd(&ccnt[t], 1);
          if (p < 8) cand[t][p] = (unsigned short)(wc*64 + j*16 + lrow);
        }
      }
    }
  __syncthreads();
  for (int it = 0; it < 16; it++){
    int t = w * 16 + it;
    int cnt = ccnt[t];
    int by;
    if (cnt == 1){
      by = cand[t][0];
    } else {
      const float* xr = xs + ((size_t)b * DLX + t) * DD;
      float best = -1e30f; int besty = 0;
      int n = (cnt <= 8) ? cnt : 256;
      for (int p = 0; p < n; p++){
        int c = (cnt <= 8) ? (int)cand[t][p] : p;
        const float* yr = Y + (size_t)c * DD;
        float s = 0.f;
        #pragma unroll
        for (int q = 0; q < 3; q++){
          float4 xv = *(const float4*)(xr + l*12 + q*4);
          float4 yv = *(const float4*)(yr + l*12 + q*4);
          s += xv.x*yv.x + xv.y*yv.y + xv.z*yv.z + xv.w*yv.w;
        }
        s += __shfl_xor(s, 1);  s += __shfl_xor(s, 2);  s += __shfl_xor(s, 4);
        s += __shfl_xor(s, 8);  s += __shfl_xor(s, 16); s += __shfl_xor(s, 32);
        if (s > best || (s == best && c < besty)){ best = s; besty = c; }
      }
      by = besty;
    }
    if (l == 0) widx[(size_t)bc * DLX + t] = by;
  }
}

// ---------------- 128x256 f16 MFMA GEMM, 8 waves, BK=64, XCD-swizzled (R13, verified) ----------------
// B reached via 32-bit delta from A base (adjacent ws allocs) to keep VGPR low.
// LDS rows are 128B: slot-XOR swizzle s^=(row&7) on BOTH source and read (conflict-free: R11/R13 = 0).
// MODE 0: X0h = f16(xs16 @ W0x^T + b0)               (grid 6 x 16)
// MODE 1: H0 = softplus(ys16[widx] @ W0y^T + X0h)    (grid 6 x 1024)
// MODE 2: spart = softplus(H0 @ W1^T + b1) . w2      (grid 3 x 1024)
template<int MODE>
__global__ __launch_bounds__(512) void k_gemm16(const _Float16* __restrict__ A,
        unsigned bdelta,                       // (B - A) in halves
        const int* __restrict__ widx,
        const _Float16* __restrict__ X0h,
        const float* __restrict__ bias,
        const float* __restrict__ w2,
        float* __restrict__ outF,
        _Float16* __restrict__ outH){
  constexpr int K = (MODE == 2) ? DH0 : DD;
  __shared__ __align__(16) _Float16 As[128 * 64];   // 16 KB
  __shared__ __align__(16) _Float16 Bs[256 * 64];   // 32 KB
  const int tid = threadIdx.x;
  const int gx = gridDim.x, nwg = gx * gridDim.y;
  int lin = blockIdx.x + gx * blockIdx.y;
  int swz = (lin & 7) * (nwg >> 3) + (lin >> 3);   // bijective (nwg % 8 == 0)
  const int n0  = (swz % gx) * 256;
  const int by  = swz / gx;
  const int rt0 = by * 128;
  const int l = tid & 63, w = tid >> 6;            // 8 waves
  const int wr = w >> 2, wc = w & 3;               // wave tile 64m x 64n
  const int lrow = l & 15, lg = l >> 4;

  int bc = 0, xb = 0, b = 0;
  if constexpr (MODE == 1){ bc = by >> 1; xb = (by & 1) * 128; b = bc >> 6; }

  // staging: 48 1KB-units (0..15 = A 8-row groups, 16..47 = B), 6 per wave.
  // lane l -> in-unit row (l>>3), dest slot (l&7); source slot (l&7)^(row&7).
  const int urow = l >> 3;
  const int uslot = (l & 7) ^ (urow & 7);          // pre-swizzled source slot
  unsigned goff[6];                                // halves offset from A base
  _Float16* ldst[6];
  #pragma unroll
  for (int i = 0; i < 6; i++){
    int u = w*6 + i;
    if (u < 16){
      int row = u*8 + urow;
      unsigned aoff;
      if constexpr (MODE == 1){
        int yi = widx[bc * DLX + xb + row];
        aoff = (unsigned)((bc * DLY + yi) * DD);
      } else {
        aoff = (unsigned)((rt0 + row) * K);
      }
      goff[i] = aoff + uslot*8;
      ldst[i] = (_Float16*)As + u*512;
    } else {
      int row = (u - 16)*8 + urow;
      goff[i] = bdelta + (unsigned)((n0 + row) * K) + uslot*8;
      ldst[i] = (_Float16*)Bs + (u - 16)*512;
    }
  }

  f32x4 acc[4][4];
  #pragma unroll
  for (int i = 0; i < 4; i++)
    #pragma unroll
    for (int j = 0; j < 4; j++) acc[i][j] = (f32x4){0.f,0.f,0.f,0.f};

  for (int k0 = 0; k0 < K; k0 += 64){
    __syncthreads();
    #pragma unroll
    for (int i = 0; i < 6; i++)
      gload_lds16(A + (size_t)(goff[i] + (unsigned)k0), ldst[i]);
    __syncthreads();
    __builtin_amdgcn_s_setprio(1);
    #pragma unroll
    for (int kh = 0; kh < 2; kh++){
      const int rc = ((kh*4 + lg) ^ (lrow & 7)) * 8;   // swizzled read col (halves)
      f16x8 af[4], bf[4];
      #pragma unroll
      for (int i = 0; i < 4; i++){
        af[i] = *(const f16x8*)&As[(wr*64 + i*16 + lrow)*64 + rc];
        bf[i] = *(const f16x8*)&Bs[(wc*64 + i*16 + lrow)*64 + rc];
      }
      #pragma unroll
      for (int i = 0; i < 4; i++)
        #pragma unroll
        for (int j = 0; j < 4; j++)
          acc[i][j] = __builtin_amdgcn_mfma_f32_16x16x32_f16(af[i], bf[j], acc[i][j], 0, 0, 0);
    }
    __builtin_amdgcn_s_setprio(0);
  }

  if constexpr (MODE == 0){
    #pragma unroll
    for (int mi = 0; mi < 4; mi++)
      #pragma unroll
      for (int ni = 0; ni < 4; ni++){
        int n = n0 + wc*64 + ni*16 + lrow;
        float bv = bias[n];
        #pragma unroll
        for (int r = 0; r < 4; r++){
          int m = wr*64 + mi*16 + lg*4 + r;
          outH[(size_t)(rt0 + m) * DH0 + n] = (_Float16)(acc[mi][ni][r] + bv);
        }
      }
  } else if constexpr (MODE == 1){
    #pragma unroll
    for (int mi = 0; mi < 4; mi++)
      #pragma unroll
      for (int ni = 0; ni < 4; ni++){
        int n = n0 + wc*64 + ni*16 + lrow;
        #pragma unroll
        for (int r = 0; r < 4; r++){
          int m = wr*64 + mi*16 + lg*4 + r;
          float x0v = (float)X0h[((size_t)b * DLX + xb + m) * DH0 + n];
          float v = softplusf(acc[mi][ni][r] + x0v);
          outH[(size_t)(rt0 + m) * DH0 + n] = (_Float16)v;
        }
      }
  } else {
    float p[4][4];
    #pragma unroll
    for (int mi = 0; mi < 4; mi++)
      #pragma unroll
      for (int r = 0; r < 4; r++) p[mi][r] = 0.f;
    #pragma unroll
    for (int ni = 0; ni < 4; ni++){
      int n = n0 + wc*64 + ni*16 + lrow;
      float b1v = bias[n], w2v = w2[n];
      #pragma unroll
      for (int mi = 0; mi < 4; mi++)
        #pragma unroll
        for (int r = 0; r < 4; r++)
          p[mi][r] += softplusf(acc[mi][ni][r] + b1v) * w2v;
    }
    const int nb = (int)(swz % gx);
    #pragma unroll
    for (int mi = 0; mi < 4; mi++)
      #pragma unroll
      for (int r = 0; r < 4; r++){
        float s = p[mi][r];
        s += __shfl_xor(s, 1);
        s += __shfl_xor(s, 2);
        s += __shfl_xor(s, 4);
        s += __shfl_xor(s, 8);
        if (lrow == 0){
          size_t t = (size_t)rt0 + wr*64 + mi*16 + lg*4 + r;
          outF[t * 12 + nb*4 + wc] = s;
        }
      }
  }
}

// ---------------- final reduce ----------------
__global__ __launch_bounds__(256) void k_reduce(const float* __restrict__ spart,
                                                const float* __restrict__ b2,
                                                float* __restrict__ out){
  int bc = blockIdx.x, tid = threadIdx.x;
  const float* p = spart + ((size_t)bc * DLX + tid) * 12;
  float s = 0.0f;
  #pragma unroll
  for (int j = 0; j < 12; j++) s += p[j];
  __shared__ float red[256];
  red[tid] = s;
  __syncthreads();
  for (int off = 128; off > 0; off >>= 1){
    if (tid < off) red[tid] += red[tid + off];
    __syncthreads();
  }
  if (tid == 0) out[bc] = red[0] + 256.0f * b2[0];
}

extern "C" void kernel_launch(void* const* d_in, const int* in_sizes, int n_in,
                              void* d_out, int out_size, void* d_ws, size_t ws_size,
                              hipStream_t stream){
  const float* xs = (const float*)d_in[0];
  const float* ys = (const float*)d_in[1];
  const float* W0 = (const float*)d_in[2];
  const float* b0 = (const float*)d_in[3];
  const float* W1 = (const float*)d_in[4];
  const float* b1 = (const float*)d_in[5];
  const float* W2 = (const float*)d_in[6];
  const float* b2 = (const float*)d_in[7];
  float* out = (float*)d_out;

  char* wsp = (char*)d_ws;
  size_t off = 0;
  auto alloc = [&](size_t bytes)->void*{
    void* p = wsp + off;
    off += (bytes + 255) & ~(size_t)255;
    return p;
  };
  // adjacency groups for 32-bit B-deltas: (ys16, W0yf), (xs16, W0xf), (H0, W1f)
  int* widx        = (int*)alloc((size_t)NTOK * 4);
  _Float16* ys16   = (_Float16*)alloc((size_t)NBC * DLY * DD * 2);   // 201 MB
  _Float16* W0yf   = (_Float16*)alloc((size_t)DH0 * DD * 2);
  _Float16* xs16   = (_Float16*)alloc((size_t)DB * DLX * DD * 2);
  _Float16* W0xf   = (_Float16*)alloc((size_t)DH0 * DD * 2);
  _Float16* X0h    = (_Float16*)alloc((size_t)DB * DLX * DH0 * 2);   // 6.3 MB
  float* spart     = (float*)alloc((size_t)NTOK * 12 * 4);           // 6.3 MB
  _Float16* H0     = (_Float16*)alloc((size_t)NTOK * DH0 * 2);       // 402 MB
  _Float16* W1f    = (_Float16*)alloc((size_t)DH1 * DH0 * 2);

  unsigned d0 = (unsigned)(W0xf - xs16);
  unsigned d1 = (unsigned)(W0yf - ys16);
  unsigned d2 = (unsigned)(W1f - H0);

  k_cvtall<<<dim3(2496), 256, 0, stream>>>(W0, W1, xs, W0xf, W0yf, W1f, xs16);
  k_scores4<<<dim3(NBC), 1024, 0, stream>>>(xs16, ys, xs, ys16, widx);
  k_gemm16<0><<<dim3(6, 16),   512, 0, stream>>>(xs16, d0, nullptr, nullptr, b0, nullptr, nullptr, X0h);
  k_gemm16<1><<<dim3(6, 1024), 512, 0, stream>>>(ys16, d1, widx, X0h, nullptr, nullptr, nullptr, H0);
  k_gemm16<2><<<dim3(3, 1024), 512, 0, stream>>>(H0, d2, nullptr, nullptr, b1, W2, spart, nullptr);
  k_reduce<<<NBC, 256, 0, stream>>>(spart, b2, out);
}

// Round 16
// 912.659 us; speedup vs baseline: 1.0449x; 1.0079x over previous
//
#include <hip/hip_runtime.h>
#include <stdint.h>

#define DB   8
#define DC   64
#define DLX  256
#define DLY  256
#define DD   768
#define DH0  1536
#define DH1  768
#define NBC  (DB*DC)        // 512
#define NTOK (NBC*DLX)      // 131072
#define TAU  0.25f

typedef float f32x4 __attribute__((ext_vector_type(4)));
typedef _Float16 f16x8 __attribute__((ext_vector_type(8)));
typedef _Float16 f16x4 __attribute__((ext_vector_type(4)));

// fast softplus via hw exp2/log2
__device__ __forceinline__ float softplusf(float x){
  float t = __builtin_amdgcn_exp2f(-fabsf(x) * 1.44269504f);
  return fmaxf(x, 0.0f) + 0.69314718f * __builtin_amdgcn_logf(1.0f + t);
}

// async global->LDS, 16B per lane; lds base wave-uniform (linear dest)
__device__ __forceinline__ void gload_lds16(const void* g, void* l){
  __builtin_amdgcn_global_load_lds((const __attribute__((address_space(1))) void*)g,
                                   (__attribute__((address_space(3))) void*)l,
                                   16, 0, 0);
}

// ---------------- merged fp32 -> f16 conversion: W0x | W0y | W1 | xs in one launch ----------------
__global__ __launch_bounds__(256) void k_cvtall(const float* __restrict__ W0,
                                                const float* __restrict__ W1,
                                                const float* __restrict__ xs,
                                                _Float16* __restrict__ W0xf,
                                                _Float16* __restrict__ W0yf,
                                                _Float16* __restrict__ W1f,
                                                _Float16* __restrict__ xs16){
  const float* src; _Float16* dst; int ld, off, cols, idx;
  int bb = blockIdx.x;
  if (bb < 576){        src = W0; dst = W0xf; ld = DH0; off = 0;  cols = DD;  idx = bb*256 + threadIdx.x; }
  else if (bb < 1152){  src = W0; dst = W0yf; ld = DH0; off = DD; cols = DD;  idx = (bb-576)*256 + threadIdx.x; }
  else if (bb < 1728){  src = W1; dst = W1f;  ld = DH0; off = 0;  cols = DH0; idx = (bb-1152)*256 + threadIdx.x; }
  else {                src = xs; dst = xs16; ld = DD;  off = 0;  cols = DD;  idx = (bb-1728)*256 + threadIdx.x; }
  int r = idx / (cols >> 3), c8 = (idx % (cols >> 3)) * 8;
  const float* s = src + (size_t)r * ld + off + c8;
  float4 f0 = *(const float4*)s, f1 = *(const float4*)(s + 4);
  f16x8 v;
  v[0]=(_Float16)f0.x; v[1]=(_Float16)f0.y; v[2]=(_Float16)f0.z; v[3]=(_Float16)f0.w;
  v[4]=(_Float16)f1.x; v[5]=(_Float16)f1.y; v[6]=(_Float16)f1.z; v[7]=(_Float16)f1.w;
  *(f16x8*)(dst + (size_t)r * cols + c8) = v;
}

// ---------------- scores + fused ys->f16, raw-barrier counted-wait pipeline ----------------
// Per K-step: [B1] -> issue gload_lds(A) -> ds_write Bs -> store ys16 -> prefetch next ys regs
//             -> s_waitcnt vmcnt(3) lgkmcnt(0)  (A + ds_write landed; store+prefetch in flight)
//             -> [B2] -> ds_read frags + MFMA.
__global__ __launch_bounds__(1024, 2) void k_scores4(const _Float16* __restrict__ xs16,
                                                     const float* __restrict__ ys,
                                                     const float* __restrict__ xs,
                                                     _Float16* __restrict__ ys16,
                                                     int* __restrict__ widx){
  const int bc = blockIdx.x, b = bc >> 6;
  const float* Y = ys + (size_t)bc * DLY * DD;
  __shared__ __align__(16) _Float16 As[256 * 32];   // 16 KB
  __shared__ __align__(16) _Float16 Bs[256 * 32];   // 16 KB
  __shared__ float rmx[256][4];
  __shared__ float gm[256];
  __shared__ unsigned short cand[256][8];
  __shared__ int ccnt[256];
  const int tid = threadIdx.x;
  const int l = tid & 63, w = tid >> 6;     // 16 waves
  const int wr = w >> 2, wc = w & 3;        // wave tile 64m x 64n
  const int lrow = l & 15, lg = l >> 4;
  const int kq = (lg ^ (lrow & 3)) * 8;     // swizzled read col (halves)
  const int kg = (((l & 3) ^ ((l >> 2) & 3))) * 8;
  const _Float16* srcA = xs16 + ((size_t)b * DLX + w*16 + (l >> 2)) * DD + kg;
  const int r = tid >> 2, c8 = (tid & 3) * 8;
  const float* srcB = Y + (size_t)r * DD + c8;
  _Float16* ydst = ys16 + ((size_t)bc * DLY + r) * DD + c8;
  const int bslot = (((tid & 3) ^ (r & 3))) * 8;

  f32x4 acc[4][4];
  #pragma unroll
  for (int i = 0; i < 4; i++)
    #pragma unroll
    for (int j = 0; j < 4; j++) acc[i][j] = (f32x4){0.f,0.f,0.f,0.f};

  // prologue: first ys chunk into regs
  float4 f0 = *(const float4*)(srcB);
  float4 f1 = *(const float4*)(srcB + 4);

  for (int k0 = 0; k0 < DD; k0 += 32){
    f16x8 hv;
    hv[0]=(_Float16)f0.x; hv[1]=(_Float16)f0.y; hv[2]=(_Float16)f0.z; hv[3]=(_Float16)f0.w;
    hv[4]=(_Float16)f1.x; hv[5]=(_Float16)f1.y; hv[6]=(_Float16)f1.z; hv[7]=(_Float16)f1.w;
    __builtin_amdgcn_s_barrier();            // B1: all waves done reading As/Bs
    gload_lds16(srcA + k0, As + w*512);      // vmem (must be OLDEST of this group)
    __builtin_amdgcn_sched_barrier(0);       // pin: A-load issued before the rest
    *(f16x8*)&Bs[r*32 + bslot] = hv;         // ds_write
    *(f16x8*)(ydst + k0) = hv;               // vmem store (in flight across B2)
    if (k0 + 32 < DD){
      f0 = *(const float4*)(srcB + k0 + 32); // prefetch next chunk (in flight)
      f1 = *(const float4*)(srcB + k0 + 36);
      asm volatile("s_waitcnt vmcnt(3) lgkmcnt(0)" ::: "memory");
    } else {
      asm volatile("s_waitcnt vmcnt(1) lgkmcnt(0)" ::: "memory");
    }
    __builtin_amdgcn_sched_barrier(0);
    __builtin_amdgcn_s_barrier();            // B2: As/Bs ready for all waves
    f16x8 af[4], bf[4];
    #pragma unroll
    for (int i = 0; i < 4; i++){
      af[i] = *(const f16x8*)&As[(wr*64 + i*16 + lrow)*32 + kq];
      bf[i] = *(const f16x8*)&Bs[(wc*64 + i*16 + lrow)*32 + kq];
    }
    #pragma unroll
    for (int i = 0; i < 4; i++)
      #pragma unroll
      for (int j = 0; j < 4; j++)
        acc[i][j] = __builtin_amdgcn_mfma_f32_16x16x32_f16(af[i], bf[j], acc[i][j], 0, 0, 0);
  }

  #pragma unroll
  for (int i = 0; i < 4; i++)
    #pragma unroll
    for (int r2 = 0; r2 < 4; r2++){
      float m = fmaxf(fmaxf(acc[i][0][r2], acc[i][1][r2]), fmaxf(acc[i][2][r2], acc[i][3][r2]));
      m = fmaxf(m, __shfl_xor(m, 1));
      m = fmaxf(m, __shfl_xor(m, 2));
      m = fmaxf(m, __shfl_xor(m, 4));
      m = fmaxf(m, __shfl_xor(m, 8));
      if (lrow == 0) rmx[wr*64 + i*16 + lg*4 + r2][wc] = m;
    }
  __syncthreads();
  if (tid < 256){
    gm[tid] = fmaxf(fmaxf(rmx[tid][0], rmx[tid][1]), fmaxf(rmx[tid][2], rmx[tid][3]));
    ccnt[tid] = 0;
  }
  __syncthreads();
  #pragma unroll
  for (int i = 0; i < 4; i++)
    #pragma unroll
    for (int r2 = 0; r2 < 4; r2++){
      int t = wr*64 + i*16 + lg*4 + r2;
      float thr = gm[t] - TAU;
      #pragma unroll
      for (int j = 0; j < 4; j++){
        float s = acc[i][j][r2];
        if (s >= thr){
          int p = atomicAdd(&ccnt[t], 1);
          if (p < 8) cand[t][p] = (unsigned short)(wc*64 + j*16 + lrow);
        }
      }
    }
  __syncthreads();
  for (int it = 0; it < 16; it++){
    int t = w * 16 + it;
    int cnt = ccnt[t];
    int by;
    if (cnt == 1){
      by = cand[t][0];
    } else {
      const float* xr = xs + ((size_t)b * DLX + t) * DD;
      float best = -1e30f; int besty = 0;
      int n = (cnt <= 8) ? cnt : 256;
      for (int p = 0; p < n; p++){
        int c = (cnt <= 8) ? (int)cand[t][p] : p;
        const float* yr = Y + (size_t)c * DD;
        float s = 0.f;
        #pragma unroll
        for (int q = 0; q < 3; q++){
          float4 xv = *(const float4*)(xr + l*12 + q*4);
          float4 yv = *(const float4*)(yr + l*12 + q*4);
          s += xv.x*yv.x + xv.y*yv.y + xv.z*yv.z + xv.w*yv.w;
        }
        s += __shfl_xor(s, 1);  s += __shfl_xor(s, 2);  s += __shfl_xor(s, 4);
        s += __shfl_xor(s, 8);  s += __shfl_xor(s, 16); s += __shfl_xor(s, 32);
        if (s > best || (s == best && c < besty)){ best = s; besty = c; }
      }
      by = besty;
    }
    if (l == 0) widx[(size_t)bc * DLX + t] = by;
  }
}

// ---------------- 128x256 f16 MFMA GEMM, 8 waves, BK=64, XCD-swizzled (R13/R15, verified) ----------------
template<int MODE>
__global__ __launch_bounds__(512) void k_gemm16(const _Float16* __restrict__ A,
        unsigned bdelta,                       // (B - A) in halves
        const int* __restrict__ widx,
        const _Float16* __restrict__ X0h,
        const float* __restrict__ bias,
        const float* __restrict__ w2,
        float* __restrict__ outF,
        _Float16* __restrict__ outH){
  constexpr int K = (MODE == 2) ? DH0 : DD;
  __shared__ __align__(16) _Float16 As[128 * 64];   // 16 KB
  __shared__ __align__(16) _Float16 Bs[256 * 64];   // 32 KB
  const int tid = threadIdx.x;
  const int gx = gridDim.x, nwg = gx * gridDim.y;
  int lin = blockIdx.x + gx * blockIdx.y;
  int swz = (lin & 7) * (nwg >> 3) + (lin >> 3);   // bijective (nwg % 8 == 0)
  const int n0  = (swz % gx) * 256;
  const int by  = swz / gx;
  const int rt0 = by * 128;
  const int l = tid & 63, w = tid >> 6;            // 8 waves
  const int wr = w >> 2, wc = w & 3;               // wave tile 64m x 64n
  const int lrow = l & 15, lg = l >> 4;

  int bc = 0, xb = 0, b = 0;
  if constexpr (MODE == 1){ bc = by >> 1; xb = (by & 1) * 128; b = bc >> 6; }

  const int urow = l >> 3;
  const int uslot = (l & 7) ^ (urow & 7);          // pre-swizzled source slot
  unsigned goff[6];
  _Float16* ldst[6];
  #pragma unroll
  for (int i = 0; i < 6; i++){
    int u = w*6 + i;
    if (u < 16){
      int row = u*8 + urow;
      unsigned aoff;
      if constexpr (MODE == 1){
        int yi = widx[bc * DLX + xb + row];
        aoff = (unsigned)((bc * DLY + yi) * DD);
      } else {
        aoff = (unsigned)((rt0 + row) * K);
      }
      goff[i] = aoff + uslot*8;
      ldst[i] = (_Float16*)As + u*512;
    } else {
      int row = (u - 16)*8 + urow;
      goff[i] = bdelta + (unsigned)((n0 + row) * K) + uslot*8;
      ldst[i] = (_Float16*)Bs + (u - 16)*512;
    }
  }

  f32x4 acc[4][4];
  #pragma unroll
  for (int i = 0; i < 4; i++)
    #pragma unroll
    for (int j = 0; j < 4; j++) acc[i][j] = (f32x4){0.f,0.f,0.f,0.f};

  for (int k0 = 0; k0 < K; k0 += 64){
    __syncthreads();
    #pragma unroll
    for (int i = 0; i < 6; i++)
      gload_lds16(A + (size_t)(goff[i] + (unsigned)k0), ldst[i]);
    __syncthreads();
    __builtin_amdgcn_s_setprio(1);
    #pragma unroll
    for (int kh = 0; kh < 2; kh++){
      const int rc = ((kh*4 + lg) ^ (lrow & 7)) * 8;   // swizzled read col (halves)
      f16x8 af[4], bf[4];
      #pragma unroll
      for (int i = 0; i < 4; i++){
        af[i] = *(const f16x8*)&As[(wr*64 + i*16 + lrow)*64 + rc];
        bf[i] = *(const f16x8*)&Bs[(wc*64 + i*16 + lrow)*64 + rc];
      }
      #pragma unroll
      for (int i = 0; i < 4; i++)
        #pragma unroll
        for (int j = 0; j < 4; j++)
          acc[i][j] = __builtin_amdgcn_mfma_f32_16x16x32_f16(af[i], bf[j], acc[i][j], 0, 0, 0);
    }
    __builtin_amdgcn_s_setprio(0);
  }

  if constexpr (MODE == 0){
    #pragma unroll
    for (int mi = 0; mi < 4; mi++)
      #pragma unroll
      for (int ni = 0; ni < 4; ni++){
        int n = n0 + wc*64 + ni*16 + lrow;
        float bv = bias[n];
        #pragma unroll
        for (int r = 0; r < 4; r++){
          int m = wr*64 + mi*16 + lg*4 + r;
          outH[(size_t)(rt0 + m) * DH0 + n] = (_Float16)(acc[mi][ni][r] + bv);
        }
      }
  } else if constexpr (MODE == 1){
    #pragma unroll
    for (int mi = 0; mi < 4; mi++)
      #pragma unroll
      for (int ni = 0; ni < 4; ni++){
        int n = n0 + wc*64 + ni*16 + lrow;
        #pragma unroll
        for (int r = 0; r < 4; r++){
          int m = wr*64 + mi*16 + lg*4 + r;
          float x0v = (float)X0h[((size_t)b * DLX + xb + m) * DH0 + n];
          float v = softplusf(acc[mi][ni][r] + x0v);
          outH[(size_t)(rt0 + m) * DH0 + n] = (_Float16)v;
        }
      }
  } else {
    float p[4][4];
    #pragma unroll
    for (int mi = 0; mi < 4; mi++)
      #pragma unroll
      for (int r = 0; r < 4; r++) p[mi][r] = 0.f;
    #pragma unroll
    for (int ni = 0; ni < 4; ni++){
      int n = n0 + wc*64 + ni*16 + lrow;
      float b1v = bias[n], w2v = w2[n];
      #pragma unroll
      for (int mi = 0; mi < 4; mi++)
        #pragma unroll
        for (int r = 0; r < 4; r++)
          p[mi][r] += softplusf(acc[mi][ni][r] + b1v) * w2v;
    }
    const int nb = (int)(swz % gx);
    #pragma unroll
    for (int mi = 0; mi < 4; mi++)
      #pragma unroll
      for (int r = 0; r < 4; r++){
        float s = p[mi][r];
        s += __shfl_xor(s, 1);
        s += __shfl_xor(s, 2);
        s += __shfl_xor(s, 4);
        s += __shfl_xor(s, 8);
        if (lrow == 0){
          size_t t = (size_t)rt0 + wr*64 + mi*16 + lg*4 + r;
          outF[t * 12 + nb*4 + wc] = s;
        }
      }
  }
}

// ---------------- final reduce ----------------
__global__ __launch_bounds__(256) void k_reduce(const float* __restrict__ spart,
                                                const float* __restrict__ b2,
                                                float* __restrict__ out){
  int bc = blockIdx.x, tid = threadIdx.x;
  const float* p = spart + ((size_t)bc * DLX + tid) * 12;
  float s = 0.0f;
  #pragma unroll
  for (int j = 0; j < 12; j++) s += p[j];
  __shared__ float red[256];
  red[tid] = s;
  __syncthreads();
  for (int off = 128; off > 0; off >>= 1){
    if (tid < off) red[tid] += red[tid + off];
    __syncthreads();
  }
  if (tid == 0) out[bc] = red[0] + 256.0f * b2[0];
}

extern "C" void kernel_launch(void* const* d_in, const int* in_sizes, int n_in,
                              void* d_out, int out_size, void* d_ws, size_t ws_size,
                              hipStream_t stream){
  const float* xs = (const float*)d_in[0];
  const float* ys = (const float*)d_in[1];
  const float* W0 = (const float*)d_in[2];
  const float* b0 = (const float*)d_in[3];
  const float* W1 = (const float*)d_in[4];
  const float* b1 = (const float*)d_in[5];
  const float* W2 = (const float*)d_in[6];
  const float* b2 = (const float*)d_in[7];
  float* out = (float*)d_out;

  char* wsp = (char*)d_ws;
  size_t off = 0;
  auto alloc = [&](size_t bytes)->void*{
    void* p = wsp + off;
    off += (bytes + 255) & ~(size_t)255;
    return p;
  };
  // adjacency groups for 32-bit B-deltas: (ys16, W0yf), (xs16, W0xf), (H0, W1f)
  int* widx        = (int*)alloc((size_t)NTOK * 4);
  _Float16* ys16   = (_Float16*)alloc((size_t)NBC * DLY * DD * 2);   // 201 MB
  _Float16* W0yf   = (_Float16*)alloc((size_t)DH0 * DD * 2);
  _Float16* xs16   = (_Float16*)alloc((size_t)DB * DLX * DD * 2);
  _Float16* W0xf   = (_Float16*)alloc((size_t)DH0 * DD * 2);
  _Float16* X0h    = (_Float16*)alloc((size_t)DB * DLX * DH0 * 2);   // 6.3 MB
  float* spart     = (float*)alloc((size_t)NTOK * 12 * 4);           // 6.3 MB
  _Float16* H0     = (_Float16*)alloc((size_t)NTOK * DH0 * 2);       // 402 MB
  _Float16* W1f    = (_Float16*)alloc((size_t)DH1 * DH0 * 2);

  unsigned d0 = (unsigned)(W0xf - xs16);
  unsigned d1 = (unsigned)(W0yf - ys16);
  unsigned d2 = (unsigned)(W1f - H0);

  k_cvtall<<<dim3(2496), 256, 0, stream>>>(W0, W1, xs, W0xf, W0yf, W1f, xs16);
  k_scores4<<<dim3(NBC), 1024, 0, stream>>>(xs16, ys, xs, ys16, widx);
  k_gemm16<0><<<dim3(6, 16),   512, 0, stream>>>(xs16, d0, nullptr, nullptr, b0, nullptr, nullptr, X0h);
  k_gemm16<1><<<dim3(6, 1024), 512, 0, stream>>>(ys16, d1, widx, X0h, nullptr, nullptr, nullptr, H0);
  k_gemm16<2><<<dim3(3, 1024), 512, 0, stream>>>(H0, d2, nullptr, nullptr, b1, W2, spart, nullptr);
  k_reduce<<<NBC, 256, 0, stream>>>(spart, b2, out);
}